// Round 3
// baseline (3057.898 us; speedup 1.0000x reference)
//
#include <hip/hip_runtime.h>
#include <hip/hip_bf16.h>

#define N_NODES 100000
#define N_EDGES 1600000
#define D_IN    128
#define D_HID   512
#define D_OUT   256

typedef __attribute__((ext_vector_type(8))) short bf16x8;
typedef __attribute__((ext_vector_type(4))) float f32x4;
typedef __attribute__((ext_vector_type(8))) unsigned short ushort8;

__device__ __forceinline__ short f2bf(float f) {
  union { float f; unsigned u; } un; un.f = f;
  unsigned r = un.u + 0x7fffu + ((un.u >> 16) & 1u);
  return (short)(r >> 16);
}
__device__ __forceinline__ float bf2f(unsigned short s) {
  union { unsigned u; float f; } un; un.u = ((unsigned)s) << 16; return un.f;
}
__device__ __forceinline__ void load_lds16(const void* g, void* l) {
  __builtin_amdgcn_global_load_lds(
      (const __attribute__((address_space(1))) char*)g,
      (__attribute__((address_space(3))) char*)l, 16, 0, 0);
}

// ---- prep: transpose+convert weights to bf16, zero BN sums -----------------
__global__ __launch_bounds__(256) void k_prep(const float* __restrict__ w1,
                                              const float* __restrict__ w2,
                                              short* __restrict__ w1t,
                                              short* __restrict__ w2t,
                                              float* __restrict__ s1,
                                              float* __restrict__ s2) {
  int gid = blockIdx.x * 256 + threadIdx.x;
  if (gid < D_IN * D_HID) {              // w1t[n*128+k] = w1[k*512+n]
    int n = gid >> 7, k = gid & 127;
    w1t[gid] = f2bf(w1[k * D_HID + n]);
  }
  int g2 = gid - D_IN * D_HID;
  if (g2 >= 0 && g2 < D_HID * D_OUT) {   // w2t[n*512+k] = w2[k*256+n]
    int n = g2 >> 9, k = g2 & 511;
    w2t[g2] = f2bf(w2[k * D_OUT + n]);
  }
  if (gid < D_HID) { s1[gid] = 0.f; s2[gid] = 0.f; }
}

// ---- agg = (1+eps)*x -------------------------------------------------------
__global__ __launch_bounds__(256) void k_init(const float* __restrict__ x,
                                              float* __restrict__ agg) {
  int gid = blockIdx.x * 256 + threadIdx.x;
  const int total = N_NODES * D_IN / 4;
  if (gid < total) {
    float4 v = reinterpret_cast<const float4*>(x)[gid];
    const float s = 1.0f + 1e-9f;
    v.x *= s; v.y *= s; v.z *= s; v.w *= s;
    reinterpret_cast<float4*>(agg)[gid] = v;
  }
}

// ---- edge scatter: agg[dst] += x[src]*w ------------------------------------
__global__ __launch_bounds__(256) void k_scatter(const float* __restrict__ x,
                                                 const int* __restrict__ esrc,
                                                 const int* __restrict__ edst,
                                                 const float* __restrict__ ew,
                                                 float* __restrict__ agg) {
  int gid = blockIdx.x * 256 + threadIdx.x;
  int e = gid >> 5;          // 32 lanes per edge
  int c = gid & 31;          // 4 floats per lane
  if (e < N_EDGES) {
    int s = esrc[e], d = edst[e];
    float wt = ew[e];
    float4 v = *reinterpret_cast<const float4*>(x + (size_t)s * D_IN + c * 4);
    float* a = agg + (size_t)d * D_IN + c * 4;
    unsafeAtomicAdd(a + 0, v.x * wt);
    unsafeAtomicAdd(a + 1, v.y * wt);
    unsafeAtomicAdd(a + 2, v.z * wt);
    unsafeAtomicAdd(a + 3, v.w * wt);
  }
}

// ---- GEMM1: h1 = bf16(agg) @ w1 + b1, accumulate BN sums -------------------
__global__ __launch_bounds__(256) void k_gemm1(const float* __restrict__ agg,
                                               const short* __restrict__ w1t,
                                               const float* __restrict__ b1,
                                               short* __restrict__ h1,
                                               float* __restrict__ s1,
                                               float* __restrict__ s2, int M) {
  __shared__ short As[128 * 64];
  __shared__ short Bs[128 * 64];
  int t = threadIdx.x;
  int bid = blockIdx.x;
  int nt = bid & 3, mt = bid >> 2;
  int wid = t >> 6, lane = t & 63;
  int wr = wid >> 1, wc = wid & 1;
  f32x4 acc[4][4] = {};

  for (int kt = 0; kt < 2; ++kt) {
    // A: reg-staged f32->bf16
    #pragma unroll
    for (int i = 0; i < 8; ++i) {
      int idx = i * 1024 + t * 4;
      int row = idx >> 6, k = idx & 63;
      int grow = mt * 128 + row;
      short4 sv = {0, 0, 0, 0};
      if (grow < M) {
        float4 v = *reinterpret_cast<const float4*>(agg + (size_t)grow * D_IN + kt * 64 + k);
        sv.x = f2bf(v.x); sv.y = f2bf(v.y); sv.z = f2bf(v.z); sv.w = f2bf(v.w);
      }
      *reinterpret_cast<short4*>(As + idx) = sv;
    }
    // B: async global->LDS, [n][k] layout
    #pragma unroll
    for (int i = 0; i < 4; ++i) {
      int c = wid * 4 + i;
      int row = c * 8 + (lane >> 3);
      const short* g = w1t + (size_t)(nt * 128 + row) * D_IN + kt * 64 + (lane & 7) * 8;
      load_lds16(g, Bs + c * 512);
    }
    __syncthreads();
    #pragma unroll
    for (int kk = 0; kk < 2; ++kk) {
      bf16x8 af[4], bfr[4];
      #pragma unroll
      for (int mf = 0; mf < 4; ++mf)
        af[mf] = *reinterpret_cast<const bf16x8*>(As + (wr * 64 + mf * 16 + (lane & 15)) * 64 + kk * 32 + (lane >> 4) * 8);
      #pragma unroll
      for (int nf = 0; nf < 4; ++nf)
        bfr[nf] = *reinterpret_cast<const bf16x8*>(Bs + (wc * 64 + nf * 16 + (lane & 15)) * 64 + kk * 32 + (lane >> 4) * 8);
      #pragma unroll
      for (int mf = 0; mf < 4; ++mf)
        #pragma unroll
        for (int nf = 0; nf < 4; ++nf)
          acc[mf][nf] = __builtin_amdgcn_mfma_f32_16x16x32_bf16(af[mf], bfr[nf], acc[mf][nf], 0, 0, 0);
    }
    __syncthreads();
  }

  int colbase = nt * 128 + wc * 64;
  float ps[4] = {0, 0, 0, 0}, ps2[4] = {0, 0, 0, 0};
  #pragma unroll
  for (int mf = 0; mf < 4; ++mf)
    #pragma unroll
    for (int nf = 0; nf < 4; ++nf) {
      int col = colbase + nf * 16 + (lane & 15);
      float bb = b1[col];
      #pragma unroll
      for (int r = 0; r < 4; ++r) {
        int grow = mt * 128 + wr * 64 + mf * 16 + (lane >> 4) * 4 + r;
        if (grow < M) {
          float v = acc[mf][nf][r] + bb;
          h1[(size_t)grow * D_HID + col] = f2bf(v);
          ps[nf] += v; ps2[nf] += v * v;
        }
      }
    }
  #pragma unroll
  for (int nf = 0; nf < 4; ++nf) {
    float a = ps[nf], b = ps2[nf];
    a += __shfl_xor(a, 16); a += __shfl_xor(a, 32);
    b += __shfl_xor(b, 16); b += __shfl_xor(b, 32);
    if ((lane >> 4) == 0) {
      int col = colbase + nf * 16 + lane;
      unsafeAtomicAdd(&s1[col], a);
      unsafeAtomicAdd(&s2[col], b);
    }
  }
}

// ---- BN params: a = gamma*rsqrt(var+eps), c = beta - mean*a ----------------
__global__ void k_bn(const float* __restrict__ s1, const float* __restrict__ s2,
                     const float* __restrict__ gamma, const float* __restrict__ beta,
                     float* __restrict__ A, float* __restrict__ C) {
  int i = threadIdx.x;
  float inv_n = 1.0f / (float)N_NODES;
  float mean = s1[i] * inv_n;
  float var = s2[i] * inv_n - mean * mean;
  float a = gamma[i] * rsqrtf(var + 1e-5f);
  A[i] = a;
  C[i] = beta[i] - mean * a;
}

// ---- GEMM2: out = relu(h1*a+c) @ w2 + b2 -----------------------------------
__global__ __launch_bounds__(256) void k_gemm2(const unsigned short* __restrict__ h1,
                                               const short* __restrict__ w2t,
                                               const float* __restrict__ b2,
                                               const float* __restrict__ Abn,
                                               const float* __restrict__ Cbn,
                                               float* __restrict__ out, int M) {
  __shared__ short As[128 * 64];
  __shared__ short Bs[128 * 64];
  __shared__ float aL[D_HID], cL[D_HID];
  int t = threadIdx.x;
  for (int i = t; i < D_HID; i += 256) { aL[i] = Abn[i]; cL[i] = Cbn[i]; }
  __syncthreads();

  int bid = blockIdx.x;
  int nt = bid & 1, mt = bid >> 1;
  int wid = t >> 6, lane = t & 63;
  int wr = wid >> 1, wc = wid & 1;
  f32x4 acc[4][4] = {};

  for (int kt = 0; kt < 8; ++kt) {
    // A: reg-staged bf16 with fused BN-apply + ReLU
    // 4 iters x 256 threads x 8 shorts = 8192 = full 128x64 tile (hole-free)
    #pragma unroll
    for (int i = 0; i < 4; ++i) {
      int idx = i * 2048 + t * 8;
      int row = idx >> 6, k = idx & 63;
      int grow = mt * 128 + row;
      ushort8 res = {};
      if (grow < M) {
        ushort8 u = *reinterpret_cast<const ushort8*>(h1 + (size_t)grow * D_HID + kt * 64 + k);
        #pragma unroll
        for (int j = 0; j < 8; ++j) {
          int gk = kt * 64 + k + j;
          float v = bf2f(u[j]) * aL[gk] + cL[gk];
          v = fmaxf(v, 0.f);
          res[j] = (unsigned short)f2bf(v);
        }
      }
      *reinterpret_cast<ushort8*>(As + idx) = res;
    }
    // B: async global->LDS
    #pragma unroll
    for (int i = 0; i < 4; ++i) {
      int c = wid * 4 + i;
      int row = c * 8 + (lane >> 3);
      const short* g = w2t + (size_t)(nt * 128 + row) * D_HID + kt * 64 + (lane & 7) * 8;
      load_lds16(g, Bs + c * 512);
    }
    __syncthreads();
    #pragma unroll
    for (int kk = 0; kk < 2; ++kk) {
      bf16x8 af[4], bfr[4];
      #pragma unroll
      for (int mf = 0; mf < 4; ++mf)
        af[mf] = *reinterpret_cast<const bf16x8*>(As + (wr * 64 + mf * 16 + (lane & 15)) * 64 + kk * 32 + (lane >> 4) * 8);
      #pragma unroll
      for (int nf = 0; nf < 4; ++nf)
        bfr[nf] = *reinterpret_cast<const bf16x8*>(Bs + (wc * 64 + nf * 16 + (lane & 15)) * 64 + kk * 32 + (lane >> 4) * 8);
      #pragma unroll
      for (int mf = 0; mf < 4; ++mf)
        #pragma unroll
        for (int nf = 0; nf < 4; ++nf)
          acc[mf][nf] = __builtin_amdgcn_mfma_f32_16x16x32_bf16(af[mf], bfr[nf], acc[mf][nf], 0, 0, 0);
    }
    __syncthreads();
  }

  int colbase = nt * 128 + wc * 64;
  #pragma unroll
  for (int mf = 0; mf < 4; ++mf)
    #pragma unroll
    for (int nf = 0; nf < 4; ++nf) {
      int col = colbase + nf * 16 + (lane & 15);
      float bb = b2[col];
      #pragma unroll
      for (int r = 0; r < 4; ++r) {
        int grow = mt * 128 + wr * 64 + mf * 16 + (lane >> 4) * 4 + r;
        if (grow < M) out[(size_t)grow * D_OUT + col] = acc[mf][nf][r] + bb;
      }
    }
}

extern "C" void kernel_launch(void* const* d_in, const int* in_sizes, int n_in,
                              void* d_out, int out_size, void* d_ws, size_t ws_size,
                              hipStream_t stream) {
  const float* x    = (const float*)d_in[0];
  const int* esrc   = (const int*)d_in[1];
  const int* edst   = (const int*)d_in[2];
  const float* ew   = (const float*)d_in[3];
  const float* w1   = (const float*)d_in[4];
  const float* b1   = (const float*)d_in[5];
  const float* gamma= (const float*)d_in[6];
  const float* beta = (const float*)d_in[7];
  const float* w2   = (const float*)d_in[8];
  const float* b2   = (const float*)d_in[9];
  float* out = (float*)d_out;

  float* agg = (float*)d_ws;                                   // N*128 f32
  short* h1  = (short*)(agg + (size_t)N_NODES * D_IN);         // N*512 bf16
  short* w1t = h1 + (size_t)N_NODES * D_HID;                   // 128*512 bf16
  short* w2t = w1t + D_IN * D_HID;                             // 512*256 bf16
  float* s1  = (float*)(w2t + D_HID * D_OUT);                  // 512 f32
  float* s2  = s1 + D_HID;
  float* Abn = s2 + D_HID;
  float* Cbn = Abn + D_HID;

  const int MT = (N_NODES + 127) / 128;  // 782

  k_prep<<<(D_IN * D_HID + D_HID * D_OUT + 255) / 256, 256, 0, stream>>>(w1, w2, w1t, w2t, s1, s2);
  k_init<<<(N_NODES * D_IN / 4 + 255) / 256, 256, 0, stream>>>(x, agg);
  k_scatter<<<N_EDGES * 32 / 256, 256, 0, stream>>>(x, esrc, edst, ew, agg);
  k_gemm1<<<MT * 4, 256, 0, stream>>>(agg, w1t, b1, h1, s1, s2, N_NODES);
  k_bn<<<1, D_HID, 0, stream>>>(s1, s2, gamma, beta, Abn, Cbn);
  k_gemm2<<<MT * 2, 256, 0, stream>>>((const unsigned short*)h1, w2t, b2, Abn, Cbn, out, N_NODES);
}

// Round 4
// 726.801 us; speedup vs baseline: 4.2073x; 4.2073x over previous
//
#include <hip/hip_runtime.h>
#include <hip/hip_bf16.h>

#define N_NODES 100000
#define N_EDGES 1600000
#define D_IN    128
#define D_HID   512
#define D_OUT   256

typedef __attribute__((ext_vector_type(8))) short bf16x8;
typedef __attribute__((ext_vector_type(4))) float f32x4;
typedef __attribute__((ext_vector_type(8))) unsigned short ushort8;

__device__ __forceinline__ short f2bf(float f) {
  union { float f; unsigned u; } un; un.f = f;
  unsigned r = un.u + 0x7fffu + ((un.u >> 16) & 1u);
  return (short)(r >> 16);
}
__device__ __forceinline__ float bf2f(unsigned short s) {
  union { unsigned u; float f; } un; un.u = ((unsigned)s) << 16; return un.f;
}
__device__ __forceinline__ void load_lds16(const void* g, void* l) {
  __builtin_amdgcn_global_load_lds(
      (const __attribute__((address_space(1))) char*)g,
      (__attribute__((address_space(3))) char*)l, 16, 0, 0);
}

// ---- prep: transpose+convert weights to bf16, zero BN sums + deg -----------
__global__ __launch_bounds__(256) void k_prep(const float* __restrict__ w1,
                                              const float* __restrict__ w2,
                                              short* __restrict__ w1t,
                                              short* __restrict__ w2t,
                                              float* __restrict__ s1,
                                              float* __restrict__ s2,
                                              int* __restrict__ deg) {
  int gid = blockIdx.x * 256 + threadIdx.x;
  if (gid < D_IN * D_HID) {              // w1t[n*128+k] = w1[k*512+n]
    int n = gid >> 7, k = gid & 127;
    w1t[gid] = f2bf(w1[k * D_HID + n]);
  }
  int g2 = gid - D_IN * D_HID;
  if (g2 >= 0 && g2 < D_HID * D_OUT) {   // w2t[n*512+k] = w2[k*256+n]
    int n = g2 >> 9, k = g2 & 511;
    w2t[g2] = f2bf(w2[k * D_OUT + n]);
  }
  if (gid < D_HID) { s1[gid] = 0.f; s2[gid] = 0.f; }
  if (gid < N_NODES) deg[gid] = 0;
}

// ---- histogram of dst degrees ----------------------------------------------
__global__ __launch_bounds__(256) void k_hist(const int* __restrict__ edst,
                                              int* __restrict__ deg) {
  int e = blockIdx.x * 256 + threadIdx.x;
  if (e < N_EDGES) atomicAdd(&deg[edst[e]], 1);
}

// ---- exclusive scan (single block, 1024 threads, shfl wave-scan) -----------
__global__ __launch_bounds__(1024) void k_scan(const int* __restrict__ deg,
                                               int* __restrict__ rowptr,
                                               int* __restrict__ cursor) {
  __shared__ int wsum[16];
  __shared__ int carry_s;
  int t = threadIdx.x;
  int lane = t & 63, w = t >> 6;
  if (t == 0) carry_s = 0;
  __syncthreads();
  for (int base = 0; base < N_NODES; base += 1024) {
    int i = base + t;
    int v = (i < N_NODES) ? deg[i] : 0;
    int sv = v;
    #pragma unroll
    for (int off = 1; off < 64; off <<= 1) {
      int u = __shfl_up(sv, off);
      if (lane >= off) sv += u;
    }
    if (lane == 63) wsum[w] = sv;
    __syncthreads();
    if (t < 16) {
      int ws = wsum[t];
      int ss = ws;
      #pragma unroll
      for (int off = 1; off < 16; off <<= 1) {
        int u = __shfl_up(ss, off);
        if (t >= off) ss += u;
      }
      wsum[t] = ss - ws;  // exclusive wave offset
    }
    __syncthreads();
    int incl = sv + wsum[w];
    int carry = carry_s;
    if (i < N_NODES) {
      int excl = carry + incl - v;
      rowptr[i] = excl;
      cursor[i] = excl;
    }
    __syncthreads();
    if (t == 1023) carry_s = carry + incl;
    __syncthreads();
  }
  if (t == 0) rowptr[N_NODES] = carry_s;
}

// ---- fill CSR records (src, weight) ----------------------------------------
__global__ __launch_bounds__(256) void k_fill(const int* __restrict__ esrc,
                                              const int* __restrict__ edst,
                                              const float* __restrict__ ew,
                                              int* __restrict__ cursor,
                                              int2* __restrict__ recs) {
  int e = blockIdx.x * 256 + threadIdx.x;
  if (e < N_EDGES) {
    int d = edst[e];
    int slot = atomicAdd(&cursor[d], 1);
    int2 r;
    r.x = esrc[e];
    r.y = __float_as_int(ew[e]);
    recs[slot] = r;
  }
}

// ---- aggregate: one wave per node, gather + accumulate, write bf16 ---------
__global__ __launch_bounds__(256) void k_agg(const float* __restrict__ x,
                                             const int* __restrict__ rowptr,
                                             const int2* __restrict__ recs,
                                             unsigned short* __restrict__ aggb) {
  int gw = (blockIdx.x * 256 + threadIdx.x) >> 6;  // node id
  int lane = threadIdx.x & 63;
  if (gw >= N_NODES) return;
  int start = rowptr[gw], end = rowptr[gw + 1];
  float2 acc = *reinterpret_cast<const float2*>(x + (size_t)gw * D_IN + lane * 2);
  const float s0 = 1.0f + 1e-9f;
  acc.x *= s0; acc.y *= s0;
  for (int j = start; j < end; j += 64) {
    int cnt = end - j;
    if (cnt > 64) cnt = 64;
    int src = 0; float wt = 0.f;
    if (lane < cnt) {
      int2 r = recs[j + lane];
      src = r.x;
      wt = __int_as_float(r.y);
    }
    for (int jj = 0; jj < cnt; ++jj) {
      int s = __shfl(src, jj);
      float ww = __shfl(wt, jj);
      float2 xv = *reinterpret_cast<const float2*>(x + (size_t)s * D_IN + lane * 2);
      acc.x += ww * xv.x;
      acc.y += ww * xv.y;
    }
  }
  ushort2 o;
  o.x = (unsigned short)f2bf(acc.x);
  o.y = (unsigned short)f2bf(acc.y);
  *reinterpret_cast<ushort2*>(aggb + (size_t)gw * D_IN + lane * 2) = o;
}

// ---- GEMM1: h1 = aggb @ w1 + b1, accumulate BN sums ------------------------
__global__ __launch_bounds__(256) void k_gemm1(const unsigned short* __restrict__ aggb,
                                               const short* __restrict__ w1t,
                                               const float* __restrict__ b1,
                                               short* __restrict__ h1,
                                               float* __restrict__ s1,
                                               float* __restrict__ s2, int M) {
  __shared__ short As[128 * 64];
  __shared__ short Bs[128 * 64];
  int t = threadIdx.x;
  int bid = blockIdx.x;
  int nt = bid & 3, mt = bid >> 2;
  int wid = t >> 6, lane = t & 63;
  int wr = wid >> 1, wc = wid & 1;
  f32x4 acc[4][4] = {};

  for (int kt = 0; kt < 2; ++kt) {
    // A: async global->LDS (bf16 rows; OOB rows read ws interior, write-guarded)
    #pragma unroll
    for (int i = 0; i < 4; ++i) {
      int c = wid * 4 + i;
      int row = c * 8 + (lane >> 3);
      const unsigned short* g = aggb + (size_t)(mt * 128 + row) * D_IN + kt * 64 + (lane & 7) * 8;
      load_lds16(g, As + c * 512);
    }
    // B: async global->LDS, [n][k] layout
    #pragma unroll
    for (int i = 0; i < 4; ++i) {
      int c = wid * 4 + i;
      int row = c * 8 + (lane >> 3);
      const short* g = w1t + (size_t)(nt * 128 + row) * D_IN + kt * 64 + (lane & 7) * 8;
      load_lds16(g, Bs + c * 512);
    }
    __syncthreads();
    #pragma unroll
    for (int kk = 0; kk < 2; ++kk) {
      bf16x8 af[4], bfr[4];
      #pragma unroll
      for (int mf = 0; mf < 4; ++mf)
        af[mf] = *reinterpret_cast<const bf16x8*>(As + (wr * 64 + mf * 16 + (lane & 15)) * 64 + kk * 32 + (lane >> 4) * 8);
      #pragma unroll
      for (int nf = 0; nf < 4; ++nf)
        bfr[nf] = *reinterpret_cast<const bf16x8*>(Bs + (wc * 64 + nf * 16 + (lane & 15)) * 64 + kk * 32 + (lane >> 4) * 8);
      #pragma unroll
      for (int mf = 0; mf < 4; ++mf)
        #pragma unroll
        for (int nf = 0; nf < 4; ++nf)
          acc[mf][nf] = __builtin_amdgcn_mfma_f32_16x16x32_bf16(af[mf], bfr[nf], acc[mf][nf], 0, 0, 0);
    }
    __syncthreads();
  }

  int colbase = nt * 128 + wc * 64;
  float ps[4] = {0, 0, 0, 0}, ps2[4] = {0, 0, 0, 0};
  #pragma unroll
  for (int mf = 0; mf < 4; ++mf)
    #pragma unroll
    for (int nf = 0; nf < 4; ++nf) {
      int col = colbase + nf * 16 + (lane & 15);
      float bb = b1[col];
      #pragma unroll
      for (int r = 0; r < 4; ++r) {
        int grow = mt * 128 + wr * 64 + mf * 16 + (lane >> 4) * 4 + r;
        if (grow < M) {
          float v = acc[mf][nf][r] + bb;
          h1[(size_t)grow * D_HID + col] = f2bf(v);
          ps[nf] += v; ps2[nf] += v * v;
        }
      }
    }
  #pragma unroll
  for (int nf = 0; nf < 4; ++nf) {
    float a = ps[nf], b = ps2[nf];
    a += __shfl_xor(a, 16); a += __shfl_xor(a, 32);
    b += __shfl_xor(b, 16); b += __shfl_xor(b, 32);
    if ((lane >> 4) == 0) {
      int col = colbase + nf * 16 + lane;
      unsafeAtomicAdd(&s1[col], a);
      unsafeAtomicAdd(&s2[col], b);
    }
  }
}

// ---- BN params: a = gamma*rsqrt(var+eps), c = beta - mean*a ----------------
__global__ void k_bn(const float* __restrict__ s1, const float* __restrict__ s2,
                     const float* __restrict__ gamma, const float* __restrict__ beta,
                     float* __restrict__ A, float* __restrict__ C) {
  int i = threadIdx.x;
  float inv_n = 1.0f / (float)N_NODES;
  float mean = s1[i] * inv_n;
  float var = s2[i] * inv_n - mean * mean;
  float a = gamma[i] * rsqrtf(var + 1e-5f);
  A[i] = a;
  C[i] = beta[i] - mean * a;
}

// ---- GEMM2: out = relu(h1*a+c) @ w2 + b2 -----------------------------------
__global__ __launch_bounds__(256) void k_gemm2(const unsigned short* __restrict__ h1,
                                               const short* __restrict__ w2t,
                                               const float* __restrict__ b2,
                                               const float* __restrict__ Abn,
                                               const float* __restrict__ Cbn,
                                               float* __restrict__ out, int M) {
  __shared__ short As[128 * 64];
  __shared__ short Bs[128 * 64];
  __shared__ float aL[D_HID], cL[D_HID];
  int t = threadIdx.x;
  for (int i = t; i < D_HID; i += 256) { aL[i] = Abn[i]; cL[i] = Cbn[i]; }
  __syncthreads();

  int bid = blockIdx.x;
  int nt = bid & 1, mt = bid >> 1;
  int wid = t >> 6, lane = t & 63;
  int wr = wid >> 1, wc = wid & 1;
  f32x4 acc[4][4] = {};

  for (int kt = 0; kt < 8; ++kt) {
    // A: reg-staged bf16 with fused BN-apply + ReLU (hole-free: 4*256*8 = 8192)
    #pragma unroll
    for (int i = 0; i < 4; ++i) {
      int idx = i * 2048 + t * 8;
      int row = idx >> 6, k = idx & 63;
      int grow = mt * 128 + row;
      ushort8 res = {};
      if (grow < M) {
        ushort8 u = *reinterpret_cast<const ushort8*>(h1 + (size_t)grow * D_HID + kt * 64 + k);
        #pragma unroll
        for (int j = 0; j < 8; ++j) {
          int gk = kt * 64 + k + j;
          float v = bf2f(u[j]) * aL[gk] + cL[gk];
          v = fmaxf(v, 0.f);
          res[j] = (unsigned short)f2bf(v);
        }
      }
      *reinterpret_cast<ushort8*>(As + idx) = res;
    }
    // B: async global->LDS
    #pragma unroll
    for (int i = 0; i < 4; ++i) {
      int c = wid * 4 + i;
      int row = c * 8 + (lane >> 3);
      const short* g = w2t + (size_t)(nt * 128 + row) * D_HID + kt * 64 + (lane & 7) * 8;
      load_lds16(g, Bs + c * 512);
    }
    __syncthreads();
    #pragma unroll
    for (int kk = 0; kk < 2; ++kk) {
      bf16x8 af[4], bfr[4];
      #pragma unroll
      for (int mf = 0; mf < 4; ++mf)
        af[mf] = *reinterpret_cast<const bf16x8*>(As + (wr * 64 + mf * 16 + (lane & 15)) * 64 + kk * 32 + (lane >> 4) * 8);
      #pragma unroll
      for (int nf = 0; nf < 4; ++nf)
        bfr[nf] = *reinterpret_cast<const bf16x8*>(Bs + (wc * 64 + nf * 16 + (lane & 15)) * 64 + kk * 32 + (lane >> 4) * 8);
      #pragma unroll
      for (int mf = 0; mf < 4; ++mf)
        #pragma unroll
        for (int nf = 0; nf < 4; ++nf)
          acc[mf][nf] = __builtin_amdgcn_mfma_f32_16x16x32_bf16(af[mf], bfr[nf], acc[mf][nf], 0, 0, 0);
    }
    __syncthreads();
  }

  int colbase = nt * 128 + wc * 64;
  #pragma unroll
  for (int mf = 0; mf < 4; ++mf)
    #pragma unroll
    for (int nf = 0; nf < 4; ++nf) {
      int col = colbase + nf * 16 + (lane & 15);
      float bb = b2[col];
      #pragma unroll
      for (int r = 0; r < 4; ++r) {
        int grow = mt * 128 + wr * 64 + mf * 16 + (lane >> 4) * 4 + r;
        if (grow < M) out[(size_t)grow * D_OUT + col] = acc[mf][nf][r] + bb;
      }
    }
}

extern "C" void kernel_launch(void* const* d_in, const int* in_sizes, int n_in,
                              void* d_out, int out_size, void* d_ws, size_t ws_size,
                              hipStream_t stream) {
  const float* x    = (const float*)d_in[0];
  const int* esrc   = (const int*)d_in[1];
  const int* edst   = (const int*)d_in[2];
  const float* ew   = (const float*)d_in[3];
  const float* w1   = (const float*)d_in[4];
  const float* b1   = (const float*)d_in[5];
  const float* gamma= (const float*)d_in[6];
  const float* beta = (const float*)d_in[7];
  const float* w2   = (const float*)d_in[8];
  const float* b2   = (const float*)d_in[9];
  float* out = (float*)d_out;

  char* base = (char*)d_ws;
  unsigned short* aggb = (unsigned short*)base;                 //  25,600,000 B
  short* h1  = (short*)(base + 25600000);                       // 102,400,000 B
  short* w1t = (short*)(base + 128000000);                      //     131,072 B
  short* w2t = (short*)(base + 128131072);                      //     262,144 B
  float* s1  = (float*)(base + 128393216);                      //       2,048 B
  float* s2  = (float*)(base + 128395264);
  float* Abn = (float*)(base + 128397312);
  float* Cbn = (float*)(base + 128399360);
  int* rowptr = (int*)(base + 128401408);                       // (N+1)*4 B
  int* cursor = (int*)(base + 128801416);                       // N*4 B
  int* deg    = (int*)(base + 129201416);                       // N*4 B
  int2* recs  = (int2*)(base + 129601416);                      // E*8 B -> end 142,401,416

  const int MT = (N_NODES + 127) / 128;  // 782

  k_prep<<<(D_IN * D_HID + D_HID * D_OUT + 255) / 256, 256, 0, stream>>>(w1, w2, w1t, w2t, s1, s2, deg);
  k_hist<<<(N_EDGES + 255) / 256, 256, 0, stream>>>(edst, deg);
  k_scan<<<1, 1024, 0, stream>>>(deg, rowptr, cursor);
  k_fill<<<(N_EDGES + 255) / 256, 256, 0, stream>>>(esrc, edst, ew, cursor, recs);
  k_agg<<<N_NODES * 64 / 256, 256, 0, stream>>>(x, rowptr, recs, aggb);
  k_gemm1<<<MT * 4, 256, 0, stream>>>(aggb, w1t, b1, h1, s1, s2, N_NODES);
  k_bn<<<1, D_HID, 0, stream>>>(s1, s2, gamma, beta, Abn, Cbn);
  k_gemm2<<<MT * 2, 256, 0, stream>>>((const unsigned short*)h1, w2t, b2, Abn, Cbn, out, N_NODES);
}

// Round 6
// 629.091 us; speedup vs baseline: 4.8608x; 1.1553x over previous
//
#include <hip/hip_runtime.h>
#include <hip/hip_bf16.h>

#define N_NODES 100000
#define N_EDGES 1600000
#define D_IN    128
#define D_HID   512
#define D_OUT   256
#define NB_SCAN ((N_NODES + 1023) / 1024)   // 98

typedef __attribute__((ext_vector_type(8))) short bf16x8;
typedef __attribute__((ext_vector_type(4))) float f32x4;
typedef __attribute__((ext_vector_type(8))) unsigned short ushort8;

__device__ __forceinline__ short f2bf(float f) {
  union { float f; unsigned u; } un; un.f = f;
  unsigned r = un.u + 0x7fffu + ((un.u >> 16) & 1u);
  return (short)(r >> 16);
}
__device__ __forceinline__ float bf2f(unsigned short s) {
  union { unsigned u; float f; } un; un.u = ((unsigned)s) << 16; return un.f;
}
__device__ __forceinline__ void load_lds16(const void* g, void* l) {
  __builtin_amdgcn_global_load_lds(
      (const __attribute__((address_space(1))) char*)g,
      (__attribute__((address_space(3))) char*)l, 16, 0, 0);
}

// ---- prep: transpose+convert weights to bf16, zero BN sums + deg -----------
__global__ __launch_bounds__(256) void k_prep(const float* __restrict__ w1,
                                              const float* __restrict__ w2,
                                              short* __restrict__ w1t,
                                              short* __restrict__ w2t,
                                              float* __restrict__ s1,
                                              float* __restrict__ s2,
                                              int* __restrict__ deg) {
  int gid = blockIdx.x * 256 + threadIdx.x;
  if (gid < D_IN * D_HID) {              // w1t[n*128+k] = w1[k*512+n]
    int n = gid >> 7, k = gid & 127;
    w1t[gid] = f2bf(w1[k * D_HID + n]);
  }
  int g2 = gid - D_IN * D_HID;
  if (g2 >= 0 && g2 < D_HID * D_OUT) {   // w2t[n*512+k] = w2[k*256+n]
    int n = g2 >> 9, k = g2 & 511;
    w2t[g2] = f2bf(w2[k * D_OUT + n]);
  }
  if (gid < D_HID) { s1[gid] = 0.f; s2[gid] = 0.f; }
  if (gid < N_NODES) deg[gid] = 0;
}

// ---- x -> bf16 -------------------------------------------------------------
__global__ __launch_bounds__(256) void k_xbf(const float* __restrict__ x,
                                             short* __restrict__ xb) {
  int gid = blockIdx.x * 256 + threadIdx.x;
  const int total = N_NODES * D_IN / 4;
  if (gid < total) {
    float4 v = reinterpret_cast<const float4*>(x)[gid];
    short4 o;
    o.x = f2bf(v.x); o.y = f2bf(v.y); o.z = f2bf(v.z); o.w = f2bf(v.w);
    reinterpret_cast<short4*>(xb)[gid] = o;
  }
}

// ---- histogram of dst degrees ----------------------------------------------
__global__ __launch_bounds__(256) void k_hist(const int* __restrict__ edst,
                                              int* __restrict__ deg) {
  int e = blockIdx.x * 256 + threadIdx.x;
  if (e < N_EDGES) atomicAdd(&deg[edst[e]], 1);
}

// ---- scan stage 1: per-block exclusive scan + block sums -------------------
__global__ __launch_bounds__(1024) void k_scan1(const int* __restrict__ deg,
                                                int* __restrict__ rowptr,
                                                int* __restrict__ bsum) {
  __shared__ int wsum[16];
  int t = threadIdx.x;
  int lane = t & 63, w = t >> 6;
  int i = blockIdx.x * 1024 + t;
  int v = (i < N_NODES) ? deg[i] : 0;
  int sv = v;
  #pragma unroll
  for (int off = 1; off < 64; off <<= 1) {
    int u = __shfl_up(sv, off);
    if (lane >= off) sv += u;
  }
  if (lane == 63) wsum[w] = sv;
  __syncthreads();
  if (t < 16) {
    int ws = wsum[t];
    int ss = ws;
    #pragma unroll
    for (int off = 1; off < 16; off <<= 1) {
      int u = __shfl_up(ss, off);
      if (t >= off) ss += u;
    }
    wsum[t] = ss - ws;  // exclusive wave offset
  }
  __syncthreads();
  int excl = sv - v + wsum[w];
  if (i < N_NODES) rowptr[i] = excl;          // block-local exclusive
  if (t == 1023) bsum[blockIdx.x] = excl + v; // block total
}

// ---- scan stage 2: single wave scans block sums ----------------------------
__global__ __launch_bounds__(64) void k_scan2(int* __restrict__ bsum,
                                              int* __restrict__ rowptrN) {
  int l = threadIdx.x;
  int i0 = 2 * l, i1 = 2 * l + 1;
  int v0 = (i0 < NB_SCAN) ? bsum[i0] : 0;
  int v1 = (i1 < NB_SCAN) ? bsum[i1] : 0;
  int p = v0 + v1, sv = p;
  #pragma unroll
  for (int off = 1; off < 64; off <<= 1) {
    int u = __shfl_up(sv, off);
    if (l >= off) sv += u;
  }
  int excl = sv - p;
  if (i0 < NB_SCAN) bsum[i0] = excl;
  if (i1 < NB_SCAN) bsum[i1] = excl + v0;
  if (l == 63) *rowptrN = sv;   // = N_EDGES
}

// ---- scan stage 3: add block offsets, init cursor --------------------------
__global__ __launch_bounds__(256) void k_scan3(int* __restrict__ rowptr,
                                               int* __restrict__ cursor,
                                               const int* __restrict__ bsum) {
  int i = blockIdx.x * 256 + threadIdx.x;
  if (i < N_NODES) {
    int v = rowptr[i] + bsum[i >> 10];
    rowptr[i] = v;
    cursor[i] = v;
  }
}

// ---- fill CSR records (src, weight) ----------------------------------------
__global__ __launch_bounds__(256) void k_fill(const int* __restrict__ esrc,
                                              const int* __restrict__ edst,
                                              const float* __restrict__ ew,
                                              int* __restrict__ cursor,
                                              int2* __restrict__ recs) {
  int e = blockIdx.x * 256 + threadIdx.x;
  if (e < N_EDGES) {
    int d = edst[e];
    int slot = atomicAdd(&cursor[d], 1);
    int2 r;
    r.x = esrc[e];
    r.y = __float_as_int(ew[e]);
    recs[slot] = r;
  }
}

// ---- aggregate: one wave per node, bf16 gather, write bf16 -----------------
__global__ __launch_bounds__(256) void k_agg(const unsigned short* __restrict__ xb,
                                             const int* __restrict__ rowptr,
                                             const int2* __restrict__ recs,
                                             unsigned short* __restrict__ aggb) {
  int gw = (blockIdx.x * 256 + threadIdx.x) >> 6;  // node id
  int lane = threadIdx.x & 63;
  if (gw >= N_NODES) return;
  int start = rowptr[gw], end = rowptr[gw + 1];
  ushort2 sx = *reinterpret_cast<const ushort2*>(xb + (size_t)gw * D_IN + lane * 2);
  const float s0 = 1.0f + 1e-9f;
  float a0 = bf2f(sx.x) * s0, a1 = bf2f(sx.y) * s0;
  for (int j = start; j < end; j += 64) {
    int cnt = end - j;
    if (cnt > 64) cnt = 64;
    int src = 0; float wt = 0.f;
    if (lane < cnt) {
      int2 r = recs[j + lane];
      src = r.x;
      wt = __int_as_float(r.y);
    }
    for (int jj = 0; jj < cnt; ++jj) {
      int s = __shfl(src, jj);
      float ww = __shfl(wt, jj);
      ushort2 xv = *reinterpret_cast<const ushort2*>(xb + (size_t)s * D_IN + lane * 2);
      a0 += ww * bf2f(xv.x);
      a1 += ww * bf2f(xv.y);
    }
  }
  ushort2 o;
  o.x = (unsigned short)f2bf(a0);
  o.y = (unsigned short)f2bf(a1);
  *reinterpret_cast<ushort2*>(aggb + (size_t)gw * D_IN + lane * 2) = o;
}

// ---- GEMM1: h1 = aggb @ w1 + b1, accumulate BN sums ------------------------
__global__ __launch_bounds__(256) void k_gemm1(const unsigned short* __restrict__ aggb,
                                               const short* __restrict__ w1t,
                                               const float* __restrict__ b1,
                                               short* __restrict__ h1,
                                               float* __restrict__ s1,
                                               float* __restrict__ s2, int M) {
  __shared__ short As[128 * 64];
  __shared__ short Bs[128 * 64];
  int t = threadIdx.x;
  int bid = blockIdx.x;
  int nt = bid & 3, mt = bid >> 2;
  int wid = t >> 6, lane = t & 63;
  int wr = wid >> 1, wc = wid & 1;
  f32x4 acc[4][4] = {};

  for (int kt = 0; kt < 2; ++kt) {
    // A: async global->LDS (bf16 rows; OOB rows read ws interior, write-guarded)
    #pragma unroll
    for (int i = 0; i < 4; ++i) {
      int c = wid * 4 + i;
      int row = c * 8 + (lane >> 3);
      const unsigned short* g = aggb + (size_t)(mt * 128 + row) * D_IN + kt * 64 + (lane & 7) * 8;
      load_lds16(g, As + c * 512);
    }
    // B: async global->LDS, [n][k] layout
    #pragma unroll
    for (int i = 0; i < 4; ++i) {
      int c = wid * 4 + i;
      int row = c * 8 + (lane >> 3);
      const short* g = w1t + (size_t)(nt * 128 + row) * D_IN + kt * 64 + (lane & 7) * 8;
      load_lds16(g, Bs + c * 512);
    }
    __syncthreads();
    #pragma unroll
    for (int kk = 0; kk < 2; ++kk) {
      bf16x8 af[4], bfr[4];
      #pragma unroll
      for (int mf = 0; mf < 4; ++mf)
        af[mf] = *reinterpret_cast<const bf16x8*>(As + (wr * 64 + mf * 16 + (lane & 15)) * 64 + kk * 32 + (lane >> 4) * 8);
      #pragma unroll
      for (int nf = 0; nf < 4; ++nf)
        bfr[nf] = *reinterpret_cast<const bf16x8*>(Bs + (wc * 64 + nf * 16 + (lane & 15)) * 64 + kk * 32 + (lane >> 4) * 8);
      #pragma unroll
      for (int mf = 0; mf < 4; ++mf)
        #pragma unroll
        for (int nf = 0; nf < 4; ++nf)
          acc[mf][nf] = __builtin_amdgcn_mfma_f32_16x16x32_bf16(af[mf], bfr[nf], acc[mf][nf], 0, 0, 0);
    }
    __syncthreads();
  }

  int colbase = nt * 128 + wc * 64;
  float ps[4] = {0, 0, 0, 0}, ps2[4] = {0, 0, 0, 0};
  #pragma unroll
  for (int mf = 0; mf < 4; ++mf)
    #pragma unroll
    for (int nf = 0; nf < 4; ++nf) {
      int col = colbase + nf * 16 + (lane & 15);
      float bb = b1[col];
      #pragma unroll
      for (int r = 0; r < 4; ++r) {
        int grow = mt * 128 + wr * 64 + mf * 16 + (lane >> 4) * 4 + r;
        if (grow < M) {
          float v = acc[mf][nf][r] + bb;
          h1[(size_t)grow * D_HID + col] = f2bf(v);
          ps[nf] += v; ps2[nf] += v * v;
        }
      }
    }
  #pragma unroll
  for (int nf = 0; nf < 4; ++nf) {
    float a = ps[nf], b = ps2[nf];
    a += __shfl_xor(a, 16); a += __shfl_xor(a, 32);
    b += __shfl_xor(b, 16); b += __shfl_xor(b, 32);
    if ((lane >> 4) == 0) {
      int col = colbase + nf * 16 + lane;
      unsafeAtomicAdd(&s1[col], a);
      unsafeAtomicAdd(&s2[col], b);
    }
  }
}

// ---- BN params: a = gamma*rsqrt(var+eps), c = beta - mean*a ----------------
__global__ void k_bn(const float* __restrict__ s1, const float* __restrict__ s2,
                     const float* __restrict__ gamma, const float* __restrict__ beta,
                     float* __restrict__ A, float* __restrict__ C) {
  int i = threadIdx.x;
  float inv_n = 1.0f / (float)N_NODES;
  float mean = s1[i] * inv_n;
  float var = s2[i] * inv_n - mean * mean;
  float a = gamma[i] * rsqrtf(var + 1e-5f);
  A[i] = a;
  C[i] = beta[i] - mean * a;
}

// ---- GEMM2: out = relu(h1*a+c) @ w2 + b2 -----------------------------------
__global__ __launch_bounds__(256) void k_gemm2(const unsigned short* __restrict__ h1,
                                               const short* __restrict__ w2t,
                                               const float* __restrict__ b2,
                                               const float* __restrict__ Abn,
                                               const float* __restrict__ Cbn,
                                               float* __restrict__ out, int M) {
  __shared__ short As[128 * 64];
  __shared__ short Bs[128 * 64];
  __shared__ float aL[D_HID], cL[D_HID];
  int t = threadIdx.x;
  for (int i = t; i < D_HID; i += 256) { aL[i] = Abn[i]; cL[i] = Cbn[i]; }
  __syncthreads();

  int bid = blockIdx.x;
  int nt = bid & 1, mt = bid >> 1;
  int wid = t >> 6, lane = t & 63;
  int wr = wid >> 1, wc = wid & 1;
  f32x4 acc[4][4] = {};

  for (int kt = 0; kt < 8; ++kt) {
    // A: reg-staged bf16 with fused BN-apply + ReLU (hole-free: 4*256*8 = 8192)
    #pragma unroll
    for (int i = 0; i < 4; ++i) {
      int idx = i * 2048 + t * 8;
      int row = idx >> 6, k = idx & 63;
      int grow = mt * 128 + row;
      ushort8 res = {};
      if (grow < M) {
        ushort8 u = *reinterpret_cast<const ushort8*>(h1 + (size_t)grow * D_HID + kt * 64 + k);
        #pragma unroll
        for (int j = 0; j < 8; ++j) {
          int gk = kt * 64 + k + j;
          float v = bf2f(u[j]) * aL[gk] + cL[gk];
          v = fmaxf(v, 0.f);
          res[j] = (unsigned short)f2bf(v);
        }
      }
      *reinterpret_cast<ushort8*>(As + idx) = res;
    }
    // B: async global->LDS
    #pragma unroll
    for (int i = 0; i < 4; ++i) {
      int c = wid * 4 + i;
      int row = c * 8 + (lane >> 3);
      const short* g = w2t + (size_t)(nt * 128 + row) * D_HID + kt * 64 + (lane & 7) * 8;
      load_lds16(g, Bs + c * 512);
    }
    __syncthreads();
    #pragma unroll
    for (int kk = 0; kk < 2; ++kk) {
      bf16x8 af[4], bfr[4];
      #pragma unroll
      for (int mf = 0; mf < 4; ++mf)
        af[mf] = *reinterpret_cast<const bf16x8*>(As + (wr * 64 + mf * 16 + (lane & 15)) * 64 + kk * 32 + (lane >> 4) * 8);
      #pragma unroll
      for (int nf = 0; nf < 4; ++nf)
        bfr[nf] = *reinterpret_cast<const bf16x8*>(Bs + (wc * 64 + nf * 16 + (lane & 15)) * 64 + kk * 32 + (lane >> 4) * 8);
      #pragma unroll
      for (int mf = 0; mf < 4; ++mf)
        #pragma unroll
        for (int nf = 0; nf < 4; ++nf)
          acc[mf][nf] = __builtin_amdgcn_mfma_f32_16x16x32_bf16(af[mf], bfr[nf], acc[mf][nf], 0, 0, 0);
    }
    __syncthreads();
  }

  int colbase = nt * 128 + wc * 64;
  #pragma unroll
  for (int mf = 0; mf < 4; ++mf)
    #pragma unroll
    for (int nf = 0; nf < 4; ++nf) {
      int col = colbase + nf * 16 + (lane & 15);
      float bb = b2[col];
      #pragma unroll
      for (int r = 0; r < 4; ++r) {
        int grow = mt * 128 + wr * 64 + mf * 16 + (lane >> 4) * 4 + r;
        if (grow < M) out[(size_t)grow * D_OUT + col] = acc[mf][nf][r] + bb;
      }
    }
}

extern "C" void kernel_launch(void* const* d_in, const int* in_sizes, int n_in,
                              void* d_out, int out_size, void* d_ws, size_t ws_size,
                              hipStream_t stream) {
  const float* x    = (const float*)d_in[0];
  const int* esrc   = (const int*)d_in[1];
  const int* edst   = (const int*)d_in[2];
  const float* ew   = (const float*)d_in[3];
  const float* w1   = (const float*)d_in[4];
  const float* b1   = (const float*)d_in[5];
  const float* gamma= (const float*)d_in[6];
  const float* beta = (const float*)d_in[7];
  const float* w2   = (const float*)d_in[8];
  const float* b2   = (const float*)d_in[9];
  float* out = (float*)d_out;

  char* base = (char*)d_ws;
  unsigned short* aggb = (unsigned short*)base;                 //  25,600,000 B
  short* h1  = (short*)(base + 25600000);                       // 102,400,000 B
  short* xbf = h1;  // x_bf16 aliases h1: used only before GEMM1 writes h1
  short* w1t = (short*)(base + 128000000);                      //     131,072 B
  short* w2t = (short*)(base + 128131072);                      //     262,144 B
  float* s1  = (float*)(base + 128393216);                      //       2,048 B
  float* s2  = (float*)(base + 128395264);
  float* Abn = (float*)(base + 128397312);
  float* Cbn = (float*)(base + 128399360);
  int* rowptr = (int*)(base + 128401408);                       // (N+1)*4 B
  int* cursor = (int*)(base + 128801416);                       // N*4 B
  int* deg    = (int*)(base + 129201416);                       // N*4 B
  int2* recs  = (int2*)(base + 129601416);                      // E*8 B
  int* bsum   = (int*)(base + 142401416);                       // NB_SCAN*4 B

  const int MT = (N_NODES + 127) / 128;  // 782

  k_prep<<<(D_IN * D_HID + D_HID * D_OUT + 255) / 256, 256, 0, stream>>>(w1, w2, w1t, w2t, s1, s2, deg);
  k_xbf<<<(N_NODES * D_IN / 4 + 255) / 256, 256, 0, stream>>>(x, xbf);
  k_hist<<<(N_EDGES + 255) / 256, 256, 0, stream>>>(edst, deg);
  k_scan1<<<NB_SCAN, 1024, 0, stream>>>(deg, rowptr, bsum);
  k_scan2<<<1, 64, 0, stream>>>(bsum, rowptr + N_NODES);
  k_scan3<<<(N_NODES + 255) / 256, 256, 0, stream>>>(rowptr, cursor, bsum);
  k_fill<<<(N_EDGES + 255) / 256, 256, 0, stream>>>(esrc, edst, ew, cursor, recs);
  k_agg<<<N_NODES * 64 / 256, 256, 0, stream>>>((const unsigned short*)xbf, rowptr, recs, aggb);
  k_gemm1<<<MT * 4, 256, 0, stream>>>(aggb, w1t, b1, h1, s1, s2, N_NODES);
  k_bn<<<1, D_HID, 0, stream>>>(s1, s2, gamma, beta, Abn, Cbn);
  k_gemm2<<<MT * 2, 256, 0, stream>>>((const unsigned short*)h1, w2t, b2, Abn, Cbn, out, N_NODES);
}